// Round 1
// baseline (1163.554 us; speedup 1.0000x reference)
//
#include <hip/hip_runtime.h>
#include <math.h>

#define K_CODES 512
#define D_FULL 512
#define SUB_D 128
#define N_D 4
#define B_SZ 16
#define T_SZ 2048
#define N_TOK (B_SZ * T_SZ)   // 32768
#define TILE 16               // tokens per block

// LDS: xs[128][16] (8KB), L[16][512] logits->enc (32KB), Q[128][17] staging (8.5KB)

__global__ __launch_bounds__(256) void vq_kernel(
    const float* __restrict__ x,
    const float* __restrict__ W1, const float* __restrict__ W2,
    const float* __restrict__ W3, const float* __restrict__ W4,
    const float* __restrict__ gum,
    float* __restrict__ out,
    float* __restrict__ wsum,   // [R][N_D*K] replicated accumulators
    int Rmask)                  // R-1, R power of two
{
    const int tid = threadIdx.x;
    const int g = blockIdx.y;
    const int tile = blockIdx.x;
    const int n0 = tile * TILE;
    const int b = n0 / T_SZ;
    const int t0 = n0 % T_SZ;

    const float* Wg = (g == 0) ? W1 : ((g == 1) ? W2 : ((g == 2) ? W3 : W4));

    __shared__ float xs[SUB_D * TILE];     // [j][tt], addr = j*16+tt
    __shared__ float L[TILE][K_CODES];     // logits then enc
    __shared__ float Q[SUB_D * 17];        // quant staging, padded

    // ---- load x tile: x[b, g*128+j, t0+tt] ----
    const float* xbase = x + ((size_t)b * D_FULL + g * SUB_D) * T_SZ + t0;
    #pragma unroll
    for (int it = 0; it < (SUB_D * TILE) / 256; ++it) {
        int e = tid + it * 256;
        int j = e >> 4, tt = e & 15;
        xs[e] = xbase[(size_t)j * T_SZ + tt];   // LDS addr == e: sequential, no conflict
    }
    __syncthreads();

    // ---- phase 1: logits for k1 = tid, k2 = tid+256 ----
    float acc1[TILE], acc2[TILE];
    float cs1 = 0.f, cs2 = 0.f;
    #pragma unroll
    for (int tt = 0; tt < TILE; ++tt) { acc1[tt] = 0.f; acc2[tt] = 0.f; }

    const float4* Wr1 = (const float4*)(Wg + (size_t)tid * SUB_D);
    const float4* Wr2 = (const float4*)(Wg + (size_t)(tid + 256) * SUB_D);
    #pragma unroll 4
    for (int j4 = 0; j4 < SUB_D / 4; ++j4) {
        float4 w1 = Wr1[j4];
        float4 w2 = Wr2[j4];
        cs1 += w1.x * w1.x + w1.y * w1.y + w1.z * w1.z + w1.w * w1.w;
        cs2 += w2.x * w2.x + w2.y * w2.y + w2.z * w2.z + w2.w * w2.w;
        const float4* xr0 = (const float4*)(xs + (j4 * 4 + 0) * TILE);
        const float4* xr1 = (const float4*)(xs + (j4 * 4 + 1) * TILE);
        const float4* xr2 = (const float4*)(xs + (j4 * 4 + 2) * TILE);
        const float4* xr3 = (const float4*)(xs + (j4 * 4 + 3) * TILE);
        #pragma unroll
        for (int tq = 0; tq < 4; ++tq) {
            float4 x0 = xr0[tq], x1 = xr1[tq], x2 = xr2[tq], x3 = xr3[tq];
            int tt = tq * 4;
            acc1[tt + 0] += w1.x * x0.x + w1.y * x1.x + w1.z * x2.x + w1.w * x3.x;
            acc1[tt + 1] += w1.x * x0.y + w1.y * x1.y + w1.z * x2.y + w1.w * x3.y;
            acc1[tt + 2] += w1.x * x0.z + w1.y * x1.z + w1.z * x2.z + w1.w * x3.z;
            acc1[tt + 3] += w1.x * x0.w + w1.y * x1.w + w1.z * x2.w + w1.w * x3.w;
            acc2[tt + 0] += w2.x * x0.x + w2.y * x1.x + w2.z * x2.x + w2.w * x3.x;
            acc2[tt + 1] += w2.x * x0.y + w2.y * x1.y + w2.z * x2.y + w2.w * x3.y;
            acc2[tt + 2] += w2.x * x0.z + w2.y * x1.z + w2.z * x2.z + w2.w * x3.z;
            acc2[tt + 3] += w2.x * x0.w + w2.y * x1.w + w2.z * x2.w + w2.w * x3.w;
        }
    }

    // logit = (2*cross - code_sqr + gumbel) / tau, tau=2 (in_sqr dropped: const over k)
    const float* gbase = gum + ((size_t)g * N_TOK + n0) * K_CODES;
    #pragma unroll
    for (int tt = 0; tt < TILE; ++tt) {
        float g1 = gbase[(size_t)tt * K_CODES + tid];
        float g2 = gbase[(size_t)tt * K_CODES + tid + 256];
        L[tt][tid]       = (2.f * acc1[tt] - cs1 + g1) * 0.5f;
        L[tt][tid + 256] = (2.f * acc2[tt] - cs2 + g2) * 0.5f;
    }
    __syncthreads();

    // ---- phase 2: softmax per token; wave w handles tokens 4w..4w+3 ----
    const int wave = tid >> 6, lane = tid & 63;
    #pragma unroll
    for (int tt4 = 0; tt4 < 4; ++tt4) {
        int tt = wave * 4 + tt4;
        float v[8];
        float m = -1e30f;
        #pragma unroll
        for (int i = 0; i < 8; ++i) { v[i] = L[tt][lane + 64 * i]; m = fmaxf(m, v[i]); }
        #pragma unroll
        for (int off = 32; off; off >>= 1) m = fmaxf(m, __shfl_xor(m, off));
        float s = 0.f;
        #pragma unroll
        for (int i = 0; i < 8; ++i) { v[i] = __expf(v[i] - m); s += v[i]; }
        #pragma unroll
        for (int off = 32; off; off >>= 1) s += __shfl_xor(s, off);
        float r = 1.f / s;
        #pragma unroll
        for (int i = 0; i < 8; ++i) L[tt][lane + 64 * i] = v[i] * r;
    }
    __syncthreads();

    // ---- phase 3: avg_probs partial sums -> replicated ws accumulators ----
    {
        float s1 = 0.f, s2 = 0.f;
        #pragma unroll
        for (int tt = 0; tt < TILE; ++tt) { s1 += L[tt][tid]; s2 += L[tt][tid + 256]; }
        float* dst = wsum + (size_t)(blockIdx.x & Rmask) * (N_D * K_CODES) + g * K_CODES;
        atomicAdd(dst + tid, s1);
        atomicAdd(dst + tid + 256, s2);
    }

    // ---- phase 4: quant[tt][j] = sum_k enc[tt][k] * W[k][j] ----
    {
        const int j = tid & 127, h = tid >> 7;   // h in {0,1}: tokens h*8..h*8+7
        float q[8];
        #pragma unroll
        for (int i = 0; i < 8; ++i) q[i] = 0.f;
        for (int k4 = 0; k4 < K_CODES / 4; ++k4) {
            int k = k4 * 4;
            float w0 = Wg[(size_t)(k + 0) * SUB_D + j];
            float w1v = Wg[(size_t)(k + 1) * SUB_D + j];
            float w2v = Wg[(size_t)(k + 2) * SUB_D + j];
            float w3v = Wg[(size_t)(k + 3) * SUB_D + j];
            #pragma unroll
            for (int i = 0; i < 8; ++i) {
                float4 e = *(const float4*)&L[h * 8 + i][k];
                q[i] += e.x * w0 + e.y * w1v + e.z * w2v + e.w * w3v;
            }
        }
        #pragma unroll
        for (int i = 0; i < 8; ++i) Q[j * 17 + h * 8 + i] = q[i];
    }
    __syncthreads();

    // ---- write out: out[b, g*128+j, t0+tt], 64B segments ----
    float* obase = out + ((size_t)b * D_FULL + g * SUB_D) * T_SZ + t0;
    #pragma unroll
    for (int it = 0; it < (SUB_D * TILE) / 256; ++it) {
        int e = tid + it * 256;
        int j = e >> 4, tt = e & 15;
        obase[(size_t)j * T_SZ + tt] = Q[j * 17 + tt];
    }
}

__global__ __launch_bounds__(256) void perp_kernel(
    const float* __restrict__ wsum, int R, float* __restrict__ out)
{
    const int tid = threadIdx.x;
    const int lane = tid & 63, wave = tid >> 6;
    __shared__ float red[N_D][4];
    float part[N_D];
    #pragma unroll
    for (int g = 0; g < N_D; ++g) part[g] = 0.f;

    for (int g = 0; g < N_D; ++g) {
        for (int kk = tid; kk < K_CODES; kk += 256) {
            float s = 0.f;
            for (int r = 0; r < R; ++r) s += wsum[(size_t)r * (N_D * K_CODES) + g * K_CODES + kk];
            float p = s * (1.0f / N_TOK);
            part[g] += p * logf(p + 1e-10f);
        }
    }
    #pragma unroll
    for (int g = 0; g < N_D; ++g) {
        float v = part[g];
        #pragma unroll
        for (int off = 32; off; off >>= 1) v += __shfl_xor(v, off);
        if (lane == 0) red[g][wave] = v;
    }
    __syncthreads();
    if (tid == 0) {
        float perp = 0.f;
        #pragma unroll
        for (int g = 0; g < N_D; ++g) {
            float e = red[g][0] + red[g][1] + red[g][2] + red[g][3];
            perp += __expf(-e);
        }
        out[(size_t)B_SZ * D_FULL * T_SZ] = perp;
    }
}

extern "C" void kernel_launch(void* const* d_in, const int* in_sizes, int n_in,
                              void* d_out, int out_size, void* d_ws, size_t ws_size,
                              hipStream_t stream) {
    const float* x   = (const float*)d_in[0];
    const float* W1  = (const float*)d_in[1];
    const float* W2  = (const float*)d_in[2];
    const float* W3  = (const float*)d_in[3];
    const float* W4  = (const float*)d_in[4];
    const float* gum = (const float*)d_in[5];
    float* out = (float*)d_out;
    float* wsum = (float*)d_ws;

    // replicas to spread atomic contention; power of 2, <= 64
    size_t maxR = ws_size / ((size_t)N_D * K_CODES * sizeof(float));
    int R = 1;
    while ((size_t)(R * 2) <= maxR && R < 64) R *= 2;

    hipMemsetAsync(d_ws, 0, (size_t)R * N_D * K_CODES * sizeof(float), stream);

    dim3 grid(N_TOK / TILE, N_D);
    vq_kernel<<<grid, 256, 0, stream>>>(x, W1, W2, W3, W4, gum, out, wsum, R - 1);
    perp_kernel<<<1, 256, 0, stream>>>(wsum, R, out);
}

// Round 2
// 666.001 us; speedup vs baseline: 1.7471x; 1.7471x over previous
//
#include <hip/hip_runtime.h>
#include <hip/hip_bf16.h>
#include <math.h>

#define K_CODES 512
#define D_FULL 512
#define SUB_D 128
#define N_D 4
#define B_SZ 16
#define T_SZ 2048
#define N_TOK (B_SZ * T_SZ)   // 32768
#define TILE 32               // tokens per block
#define XS_STRIDE 136         // bf16 elems per xs row (128 + 8 pad -> 4-bank rotate)
#define ENC_STRIDE 520        // bf16 elems per enc row (512 + 8 pad)
#define QS_STRIDE 33          // f32 elems per Qs row (32 + 1 pad)

typedef __attribute__((ext_vector_type(8))) short short8;
typedef __attribute__((ext_vector_type(16))) float f32x16;

__device__ __forceinline__ unsigned short f2bf(float f) {
    __hip_bfloat16 h = __float2bfloat16(f);   // RNE
    return *reinterpret_cast<unsigned short*>(&h);
}
__device__ __forceinline__ float bf2f(unsigned short u) {
    unsigned int v = ((unsigned int)u) << 16;
    return __uint_as_float(v);
}

// LDS: enc 32x520 bf16 = 33280 B (aliased by Qs 128x33 f32 = 16896 B)
//      xs  32x136 bf16 =  8704 B
//      Mred/Sred [32][4] f32 = 1024 B        total 43008 B -> 3 blocks/CU cap
#define ENC_BYTES 33280
#define XS_OFF    33280
#define RED_OFF   41984

__global__ __launch_bounds__(256) void vq_kernel(
    const float* __restrict__ x,
    const unsigned short* __restrict__ Wbf,    // [g][512][128] bf16
    const unsigned short* __restrict__ WTbf,   // [g][128][512] bf16
    const float* __restrict__ csqr,            // [g][512]
    const float* __restrict__ gum,
    float* __restrict__ out,
    float* __restrict__ wsum, int Rmask)
{
    __shared__ __align__(16) char smem[43008];
    unsigned short* enc = (unsigned short*)smem;
    unsigned short* xs  = (unsigned short*)(smem + XS_OFF);
    float* Mred = (float*)(smem + RED_OFF);    // [32 tokens][4 waves]
    float* Sred = Mred + 128;
    float* Qs   = (float*)smem;                // aliases enc (barrier-protected)

    const int tid = threadIdx.x;
    const int g = blockIdx.y;
    const int n0 = blockIdx.x * TILE;
    const int b = n0 / T_SZ;
    const int t0 = n0 % T_SZ;
    const int wave = tid >> 6, lane = tid & 63;
    const int half = lane >> 5, l31 = lane & 31;

    // ---- phase A: x tile -> LDS bf16, [token][d] ----
    const float* xbase = x + ((size_t)b * D_FULL + g * SUB_D) * T_SZ + t0;
    #pragma unroll
    for (int it = 0; it < 4; ++it) {
        int idx = tid + it * 256;          // 0..1023
        int tq = idx & 7, d = idx >> 3;    // coalesced: consecutive tid -> consecutive t
        float4 v = *(const float4*)(xbase + (size_t)d * T_SZ + tq * 4);
        int t = tq * 4;
        xs[(t + 0) * XS_STRIDE + d] = f2bf(v.x);
        xs[(t + 1) * XS_STRIDE + d] = f2bf(v.y);
        xs[(t + 2) * XS_STRIDE + d] = f2bf(v.z);
        xs[(t + 3) * XS_STRIDE + d] = f2bf(v.w);
    }
    __syncthreads();

    // ---- phase B: cross = x . W^T via MFMA 32x32x16 ----
    // A[m=lane&31][k=(lane>>5)*8+j]; B[k][n=lane&31], k=(lane>>5)*8+j
    short8 afrag[8];
    #pragma unroll
    for (int s = 0; s < 8; ++s)
        afrag[s] = *(const short8*)(xs + l31 * XS_STRIDE + s * 16 + half * 8);

    const unsigned short* Wg = Wbf + (size_t)g * K_CODES * SUB_D;
    f32x16 acc[4];
    #pragma unroll
    for (int ct = 0; ct < 4; ++ct)
        #pragma unroll
        for (int i = 0; i < 16; ++i) acc[ct][i] = 0.f;

    #pragma unroll
    for (int s = 0; s < 8; ++s) {
        #pragma unroll
        for (int ct = 0; ct < 4; ++ct) {   // 4 independent acc chains
            short8 bfrag = *(const short8*)(Wg + (size_t)(wave * 128 + ct * 32 + l31) * SUB_D
                                            + s * 16 + half * 8);
            acc[ct] = __builtin_amdgcn_mfma_f32_32x32x16_bf16(afrag[s], bfrag, acc[ct], 0, 0, 0);
        }
    }

    // ---- phase C: logits = cross - csqr/2 + gum/2, softmax over 512 codes ----
    // C layout: row=(i&3)+8*(i>>2)+4*half, col=l31
    const float* gbase = gum + ((size_t)g * N_TOK + n0) * K_CODES;
    float csq[4];
    #pragma unroll
    for (int ct = 0; ct < 4; ++ct)
        csq[ct] = csqr[g * K_CODES + wave * 128 + ct * 32 + l31];

    float tmax[16];
    #pragma unroll
    for (int i = 0; i < 16; ++i) tmax[i] = -1e30f;
    #pragma unroll
    for (int ct = 0; ct < 4; ++ct) {
        int code = wave * 128 + ct * 32 + l31;
        #pragma unroll
        for (int i = 0; i < 16; ++i) {
            int r = (i & 3) + 8 * (i >> 2) + 4 * half;
            float l = acc[ct][i] - 0.5f * csq[ct] + 0.5f * gbase[(size_t)r * K_CODES + code];
            acc[ct][i] = l;
            tmax[i] = fmaxf(tmax[i], l);
        }
    }
    #pragma unroll
    for (int i = 0; i < 16; ++i) {         // butterfly within 32-lane half
        float m = tmax[i];
        m = fmaxf(m, __shfl_xor(m, 1));  m = fmaxf(m, __shfl_xor(m, 2));
        m = fmaxf(m, __shfl_xor(m, 4));  m = fmaxf(m, __shfl_xor(m, 8));
        m = fmaxf(m, __shfl_xor(m, 16));
        tmax[i] = m;
    }
    if (l31 == 0) {
        #pragma unroll
        for (int i = 0; i < 16; ++i)
            Mred[((i & 3) + 8 * (i >> 2) + 4 * half) * 4 + wave] = tmax[i];
    }
    __syncthreads();
    #pragma unroll
    for (int i = 0; i < 16; ++i) {
        int r = (i & 3) + 8 * (i >> 2) + 4 * half;
        float4 mv = *(const float4*)&Mred[r * 4];
        tmax[i] = fmaxf(fmaxf(mv.x, mv.y), fmaxf(mv.z, mv.w));
    }
    float ssum[16];
    #pragma unroll
    for (int i = 0; i < 16; ++i) ssum[i] = 0.f;
    #pragma unroll
    for (int ct = 0; ct < 4; ++ct)
        #pragma unroll
        for (int i = 0; i < 16; ++i) {
            float e = __expf(acc[ct][i] - tmax[i]);
            acc[ct][i] = e;
            ssum[i] += e;
        }
    #pragma unroll
    for (int i = 0; i < 16; ++i) {
        float s = ssum[i];
        s += __shfl_xor(s, 1);  s += __shfl_xor(s, 2);
        s += __shfl_xor(s, 4);  s += __shfl_xor(s, 8);
        s += __shfl_xor(s, 16);
        ssum[i] = s;
    }
    if (l31 == 0) {
        #pragma unroll
        for (int i = 0; i < 16; ++i)
            Sred[((i & 3) + 8 * (i >> 2) + 4 * half) * 4 + wave] = ssum[i];
    }
    __syncthreads();
    float rinv[16];
    #pragma unroll
    for (int i = 0; i < 16; ++i) {
        int r = (i & 3) + 8 * (i >> 2) + 4 * half;
        float4 sv = *(const float4*)&Sred[r * 4];
        rinv[i] = 1.f / (sv.x + sv.y + sv.z + sv.w);
    }

    // ---- enc -> LDS bf16 + avg_probs atomics ----
    float* wrep = wsum + (size_t)(blockIdx.x & Rmask) * (N_D * K_CODES) + g * K_CODES;
    #pragma unroll
    for (int ct = 0; ct < 4; ++ct) {
        float s = 0.f;
        #pragma unroll
        for (int i = 0; i < 16; ++i) {
            int r = (i & 3) + 8 * (i >> 2) + 4 * half;
            float p = acc[ct][i] * rinv[i];
            enc[r * ENC_STRIDE + wave * 128 + ct * 32 + l31] = f2bf(p);
            s += p;
        }
        s += __shfl_xor(s, 32);            // combine halves (same code, other 16 tokens)
        if (half == 0) atomicAdd(wrep + wave * 128 + ct * 32 + l31, s);
    }
    __syncthreads();

    // ---- phase D: quant = enc . W via MFMA, wave owns 32 out-dims ----
    const unsigned short* Btrow = WTbf + (size_t)g * SUB_D * K_CODES
                                + (size_t)(wave * 32 + l31) * K_CODES + half * 8;
    f32x16 q0, q1;
    #pragma unroll
    for (int i = 0; i < 16; ++i) { q0[i] = 0.f; q1[i] = 0.f; }
    #pragma unroll
    for (int s = 0; s < 32; s += 2) {      // 2 independent chains
        short8 a0 = *(const short8*)(enc + l31 * ENC_STRIDE + (s + 0) * 16 + half * 8);
        short8 b0 = *(const short8*)(Btrow + (s + 0) * 16);
        short8 a1 = *(const short8*)(enc + l31 * ENC_STRIDE + (s + 1) * 16 + half * 8);
        short8 b1 = *(const short8*)(Btrow + (s + 1) * 16);
        q0 = __builtin_amdgcn_mfma_f32_32x32x16_bf16(a0, b0, q0, 0, 0, 0);
        q1 = __builtin_amdgcn_mfma_f32_32x32x16_bf16(a1, b1, q1, 0, 0, 0);
    }
    __syncthreads();   // all waves done reading enc before Qs overwrites it

    #pragma unroll
    for (int i = 0; i < 16; ++i) {
        int r = (i & 3) + 8 * (i >> 2) + 4 * half;
        Qs[(wave * 32 + l31) * QS_STRIDE + r] = q0[i] + q1[i];
    }
    __syncthreads();

    // ---- write out [b, g*128+j, t0+t], 128B segments ----
    float* obase = out + ((size_t)b * D_FULL + g * SUB_D) * T_SZ + t0;
    #pragma unroll
    for (int it = 0; it < 4; ++it) {
        int idx = tid + it * 256;
        int t4 = (idx & 7) * 4, j = idx >> 3;
        float4 v;
        v.x = Qs[j * QS_STRIDE + t4 + 0];
        v.y = Qs[j * QS_STRIDE + t4 + 1];
        v.z = Qs[j * QS_STRIDE + t4 + 2];
        v.w = Qs[j * QS_STRIDE + t4 + 3];
        *(float4*)(obase + (size_t)j * T_SZ + t4) = v;
    }
}

__global__ __launch_bounds__(256) void prep_kernel(
    const float* __restrict__ W1, const float* __restrict__ W2,
    const float* __restrict__ W3, const float* __restrict__ W4,
    unsigned short* __restrict__ Wbf, unsigned short* __restrict__ WTbf,
    float* __restrict__ csqr)
{
    const int g = blockIdx.x;
    const float* Wg = (g == 0) ? W1 : ((g == 1) ? W2 : ((g == 2) ? W3 : W4));
    const int tid = threadIdx.x;
    for (int idx = tid; idx < K_CODES * SUB_D; idx += 256) {
        int k = idx >> 7, d = idx & 127;
        unsigned short v = f2bf(Wg[idx]);
        Wbf[(size_t)g * K_CODES * SUB_D + idx] = v;
        WTbf[(size_t)g * SUB_D * K_CODES + (size_t)d * K_CODES + k] = v;
    }
    for (int k = tid; k < K_CODES; k += 256) {
        float s = 0.f;
        for (int d = 0; d < SUB_D; ++d) {
            float wv = bf2f(f2bf(Wg[k * SUB_D + d]));
            s += wv * wv;
        }
        csqr[g * K_CODES + k] = s;
    }
}

__global__ __launch_bounds__(256) void perp_kernel(
    const float* __restrict__ wsum, int R, float* __restrict__ out)
{
    const int tid = threadIdx.x;
    const int lane = tid & 63, wave = tid >> 6;
    __shared__ float red[N_D][4];
    float part[N_D];
    #pragma unroll
    for (int g = 0; g < N_D; ++g) part[g] = 0.f;

    for (int g = 0; g < N_D; ++g) {
        for (int kk = tid; kk < K_CODES; kk += 256) {
            float s = 0.f;
            for (int r = 0; r < R; ++r) s += wsum[(size_t)r * (N_D * K_CODES) + g * K_CODES + kk];
            float p = s * (1.0f / N_TOK);
            part[g] += p * logf(p + 1e-10f);
        }
    }
    #pragma unroll
    for (int g = 0; g < N_D; ++g) {
        float v = part[g];
        #pragma unroll
        for (int off = 32; off; off >>= 1) v += __shfl_xor(v, off);
        if (lane == 0) red[g][wave] = v;
    }
    __syncthreads();
    if (tid == 0) {
        float perp = 0.f;
        #pragma unroll
        for (int g = 0; g < N_D; ++g) {
            float e = red[g][0] + red[g][1] + red[g][2] + red[g][3];
            perp += __expf(-e);
        }
        out[(size_t)B_SZ * D_FULL * T_SZ] = perp;
    }
}

extern "C" void kernel_launch(void* const* d_in, const int* in_sizes, int n_in,
                              void* d_out, int out_size, void* d_ws, size_t ws_size,
                              hipStream_t stream) {
    const float* x   = (const float*)d_in[0];
    const float* W1  = (const float*)d_in[1];
    const float* W2  = (const float*)d_in[2];
    const float* W3  = (const float*)d_in[3];
    const float* W4  = (const float*)d_in[4];
    const float* gum = (const float*)d_in[5];
    float* out = (float*)d_out;

    // ws layout: Wbf (512KB) | WTbf (512KB) | csqr (8KB) | wsum (R * 8KB)
    unsigned short* Wbf  = (unsigned short*)d_ws;
    unsigned short* WTbf = Wbf + (size_t)N_D * K_CODES * SUB_D;
    float* csqr = (float*)(WTbf + (size_t)N_D * K_CODES * SUB_D);
    float* wsum = csqr + N_D * K_CODES;

    size_t fixed = (size_t)N_D * K_CODES * SUB_D * 2 * 2 + (size_t)N_D * K_CODES * 4;
    size_t rem = (ws_size > fixed) ? (ws_size - fixed) : 0;
    int maxR = (int)(rem / ((size_t)N_D * K_CODES * 4));
    int R = 1;
    while (R * 2 <= maxR && R < 16) R *= 2;

    hipMemsetAsync(wsum, 0, (size_t)R * N_D * K_CODES * sizeof(float), stream);
    prep_kernel<<<4, 256, 0, stream>>>(W1, W2, W3, W4, Wbf, WTbf, csqr);
    vq_kernel<<<dim3(N_TOK / TILE, N_D), 256, 0, stream>>>(x, Wbf, WTbf, csqr, gum, out, wsum, R - 1);
    perp_kernel<<<1, 256, 0, stream>>>(wsum, R, out);
}

// Round 3
// 570.254 us; speedup vs baseline: 2.0404x; 1.1679x over previous
//
#include <hip/hip_runtime.h>
#include <hip/hip_bf16.h>
#include <math.h>

#define K_CODES 512
#define D_FULL 512
#define SUB_D 128
#define N_D 4
#define B_SZ 16
#define T_SZ 2048
#define N_TOK (B_SZ * T_SZ)   // 32768
#define TILE 32               // tokens per block
#define XS_STRIDE 136         // bf16 elems per xs row (128 + 8 pad)
#define ENC_STRIDE 520        // bf16 elems per enc row (512 + 8 pad)
#define QS_STRIDE 33          // f32 elems per Qs row (32 + 1 pad)

typedef __attribute__((ext_vector_type(8))) short short8;
typedef __attribute__((ext_vector_type(16))) float f32x16;

__device__ __forceinline__ unsigned short f2bf(float f) {
    __hip_bfloat16 h = __float2bfloat16(f);   // RNE
    return *reinterpret_cast<unsigned short*>(&h);
}
__device__ __forceinline__ float bf2f(unsigned short u) {
    unsigned int v = ((unsigned int)u) << 16;
    return __uint_as_float(v);
}

// LDS map: enc [0, 33280) bf16 32x520 (aliased by Qs 128x33 f32 after phase D)
//          xs  [33280, 41984) bf16 32x136; reused as per-wave gumbel bounce scratch
//          Sred[41984, 42496) f32 [32 tokens][4 waves]
#define XS_OFF  33280
#define RED_OFF 41984
#define SMEM_SZ 42496

__global__ __launch_bounds__(256, 3) void vq_kernel(
    const float* __restrict__ x,
    const unsigned short* __restrict__ Wbf,    // [g][512][128] bf16
    const unsigned short* __restrict__ WTbf,   // [g][128][512] bf16
    const float* __restrict__ csqr,            // [g][512]
    const float* __restrict__ gum,
    float* __restrict__ out,
    float* __restrict__ wsum, int Rmask)
{
    __shared__ __align__(16) char smem[SMEM_SZ];
    unsigned short* enc = (unsigned short*)smem;
    unsigned short* xs  = (unsigned short*)(smem + XS_OFF);
    float* Sred = (float*)(smem + RED_OFF);
    float* Qs   = (float*)smem;                // aliases enc (barrier-protected)

    const int tid = threadIdx.x;
    const int g = blockIdx.y;
    const int n0 = blockIdx.x * TILE;
    const int b = n0 / T_SZ;
    const int t0 = n0 % T_SZ;
    const int wave = tid >> 6, lane = tid & 63;
    const int half = lane >> 5, l31 = lane & 31;

    // ---- phase A: x tile -> LDS bf16, [token][d] ----
    const float* xbase = x + ((size_t)b * D_FULL + g * SUB_D) * T_SZ + t0;
    #pragma unroll
    for (int it = 0; it < 4; ++it) {
        int idx = tid + it * 256;          // 0..1023
        int tq = idx & 7, d = idx >> 3;
        float4 v = *(const float4*)(xbase + (size_t)d * T_SZ + tq * 4);
        int t = tq * 4;
        xs[(t + 0) * XS_STRIDE + d] = f2bf(v.x);
        xs[(t + 1) * XS_STRIDE + d] = f2bf(v.y);
        xs[(t + 2) * XS_STRIDE + d] = f2bf(v.z);
        xs[(t + 3) * XS_STRIDE + d] = f2bf(v.w);
    }
    __syncthreads();                       // B1: xs ready

    // ---- phase B: cross = x . W^T via MFMA 32x32x16 ----
    short8 afrag[8];
    #pragma unroll
    for (int s = 0; s < 8; ++s)
        afrag[s] = *(const short8*)(xs + l31 * XS_STRIDE + s * 16 + half * 8);

    // csq loaded EARLY (before gumbel loads) so its vmcnt wait never drains them
    float csq[4];
    #pragma unroll
    for (int ct = 0; ct < 4; ++ct)
        csq[ct] = csqr[g * K_CODES + wave * 128 + ct * 32 + l31];

    __syncthreads();                       // B2: all waves done reading xs

    const unsigned short* Wg = Wbf + (size_t)g * K_CODES * SUB_D;
    f32x16 acc[4];
    #pragma unroll
    for (int ct = 0; ct < 4; ++ct)
        #pragma unroll
        for (int i = 0; i < 16; ++i) acc[ct][i] = 0.f;

    #pragma unroll
    for (int s = 0; s < 8; ++s) {
        #pragma unroll
        for (int ct = 0; ct < 4; ++ct) {
            short8 bfrag = *(const short8*)(Wg + (size_t)(wave * 128 + ct * 32 + l31) * SUB_D
                                            + s * 16 + half * 8);
            acc[ct] = __builtin_amdgcn_mfma_f32_32x32x16_bf16(afrag[s], bfrag, acc[ct], 0, 0, 0);
        }
    }

    // keep gumbel loads AFTER all W-fragment loads (in-order vmcnt: waiting on a
    // load also waits everything older -> gumbels must be the newest)
    __builtin_amdgcn_sched_barrier(0);

    // ---- gumbel slice for this wave: 32 tokens x 128 codes, 16x dwordx4 ----
    const float* gw = gum + ((size_t)g * N_TOK + n0) * K_CODES + wave * 128;
    float4 f[16];
    #pragma unroll
    for (int k = 0; k < 16; ++k)           // chunk k: rows {2k, 2k+1}, cc = 4*l31
        f[k] = *(const float4*)(gw + (size_t)(2 * k + half) * K_CODES + 4 * l31);

    // ---- bounce through per-wave scratch (xs region) + fused exp/ssum ----
    float* Sw = (float*)(smem + XS_OFF) + wave * 544;   // 2176 B per wave
    float ssum[16];
    #pragma unroll
    for (int i = 0; i < 16; ++i) ssum[i] = 0.f;

    #pragma unroll
    for (int j = 0; j < 8; ++j) {          // round j: tokens 4j..4j+3
        *(float4*)(Sw + half * 128 + 4 * l31)       = f[2 * j];      // rows 4j,4j+1
        *(float4*)(Sw + 256 + half * 128 + 4 * l31) = f[2 * j + 1];  // rows 4j+2,4j+3
        int hj = j & 1;
        if (half == hj) {                  // this half's tokens live in rows 4j+4h..+3
            int q = (j - hj) >> 1;         // = i>>2
            #pragma unroll
            for (int ct = 0; ct < 4; ++ct)
                #pragma unroll
                for (int m = 0; m < 4; ++m) {
                    float gv = Sw[m * 128 + ct * 32 + l31];
                    int i = q * 4 + m;
                    float e = __expf(acc[ct][i] - 0.5f * csq[ct] + 0.5f * gv);
                    acc[ct][i] = e;        // no max-subtract: logits bounded ~[-2, 9]
                    ssum[i] += e;
                }
        }
    }

    // ---- softmax denominator: 32-lane butterfly + cross-wave Sred ----
    #pragma unroll
    for (int i = 0; i < 16; ++i) {
        float s = ssum[i];
        s += __shfl_xor(s, 1);  s += __shfl_xor(s, 2);
        s += __shfl_xor(s, 4);  s += __shfl_xor(s, 8);
        s += __shfl_xor(s, 16);
        ssum[i] = s;
    }
    if (l31 == 0) {
        #pragma unroll
        for (int i = 0; i < 16; ++i)
            Sred[((i & 3) + 8 * (i >> 2) + 4 * half) * 4 + wave] = ssum[i];
    }
    __syncthreads();                       // B3
    float rinv[16];
    #pragma unroll
    for (int i = 0; i < 16; ++i) {
        int r = (i & 3) + 8 * (i >> 2) + 4 * half;
        float4 sv = *(const float4*)&Sred[r * 4];
        rinv[i] = 1.f / (sv.x + sv.y + sv.z + sv.w);
    }

    // ---- enc -> LDS bf16 + avg_probs atomics ----
    float* wrep = wsum + (size_t)(blockIdx.x & Rmask) * (N_D * K_CODES) + g * K_CODES;
    #pragma unroll
    for (int ct = 0; ct < 4; ++ct) {
        float s = 0.f;
        #pragma unroll
        for (int i = 0; i < 16; ++i) {
            int r = (i & 3) + 8 * (i >> 2) + 4 * half;
            float p = acc[ct][i] * rinv[i];
            enc[r * ENC_STRIDE + wave * 128 + ct * 32 + l31] = f2bf(p);
            s += p;
        }
        s += __shfl_xor(s, 32);
        if (half == 0) atomicAdd(wrep + wave * 128 + ct * 32 + l31, s);
    }
    __syncthreads();                       // B4: enc ready

    // ---- phase D: quant = enc . W via MFMA, wave owns 32 out-dims ----
    const unsigned short* Btrow = WTbf + (size_t)g * SUB_D * K_CODES
                                + (size_t)(wave * 32 + l31) * K_CODES + half * 8;
    f32x16 q0, q1;
    #pragma unroll
    for (int i = 0; i < 16; ++i) { q0[i] = 0.f; q1[i] = 0.f; }
    #pragma unroll
    for (int s = 0; s < 32; s += 2) {
        short8 a0 = *(const short8*)(enc + l31 * ENC_STRIDE + (s + 0) * 16 + half * 8);
        short8 b0 = *(const short8*)(Btrow + (s + 0) * 16);
        short8 a1 = *(const short8*)(enc + l31 * ENC_STRIDE + (s + 1) * 16 + half * 8);
        short8 b1 = *(const short8*)(Btrow + (s + 1) * 16);
        q0 = __builtin_amdgcn_mfma_f32_32x32x16_bf16(a0, b0, q0, 0, 0, 0);
        q1 = __builtin_amdgcn_mfma_f32_32x32x16_bf16(a1, b1, q1, 0, 0, 0);
    }
    __syncthreads();                       // B5: enc reads done, Qs may overwrite

    #pragma unroll
    for (int i = 0; i < 16; ++i) {
        int r = (i & 3) + 8 * (i >> 2) + 4 * half;
        Qs[(wave * 32 + l31) * QS_STRIDE + r] = q0[i] + q1[i];
    }
    __syncthreads();                       // B6

    // ---- write out [b, g*128+j, t0+t], 128B segments ----
    float* obase = out + ((size_t)b * D_FULL + g * SUB_D) * T_SZ + t0;
    #pragma unroll
    for (int it = 0; it < 4; ++it) {
        int idx = tid + it * 256;
        int t4 = (idx & 7) * 4, j = idx >> 3;
        float4 v;
        v.x = Qs[j * QS_STRIDE + t4 + 0];
        v.y = Qs[j * QS_STRIDE + t4 + 1];
        v.z = Qs[j * QS_STRIDE + t4 + 2];
        v.w = Qs[j * QS_STRIDE + t4 + 3];
        *(float4*)(obase + (size_t)j * T_SZ + t4) = v;
    }
}

__global__ __launch_bounds__(256) void prep_kernel(
    const float* __restrict__ W1, const float* __restrict__ W2,
    const float* __restrict__ W3, const float* __restrict__ W4,
    unsigned short* __restrict__ Wbf, unsigned short* __restrict__ WTbf,
    float* __restrict__ csqr)
{
    const int g = blockIdx.x, kc = blockIdx.y;   // 64 codes per block
    const float* Wg = (g == 0) ? W1 : ((g == 1) ? W2 : ((g == 2) ? W3 : W4));
    const int tid = threadIdx.x;
    const int k0 = kc * 64;
    __shared__ float tile[64][129];              // bf16-rounded values

    #pragma unroll
    for (int it = 0; it < 8; ++it) {
        int idx = tid + it * 256;                // 2048 float4 total
        int k = idx >> 5, d4 = (idx & 31) * 4;
        float4 v = *(const float4*)(Wg + (size_t)(k0 + k) * SUB_D + d4);
        unsigned short p0 = f2bf(v.x), p1 = f2bf(v.y), p2 = f2bf(v.z), p3 = f2bf(v.w);
        tile[k][d4 + 0] = bf2f(p0); tile[k][d4 + 1] = bf2f(p1);
        tile[k][d4 + 2] = bf2f(p2); tile[k][d4 + 3] = bf2f(p3);
        ushort4 pk; pk.x = p0; pk.y = p1; pk.z = p2; pk.w = p3;
        *(ushort4*)(Wbf + (size_t)g * K_CODES * SUB_D + (size_t)(k0 + k) * SUB_D + d4) = pk;
    }
    __syncthreads();

    #pragma unroll
    for (int it = 0; it < 4; ++it) {
        int idx = tid + it * 256;                // 1024 short8 chunks
        int d = idx >> 3, c8 = (idx & 7) * 8;
        union { unsigned short u[8]; short8 v; } pk;
        #pragma unroll
        for (int j = 0; j < 8; ++j) pk.u[j] = f2bf(tile[c8 + j][d]);
        *(short8*)(WTbf + (size_t)g * SUB_D * K_CODES + (size_t)d * K_CODES + k0 + c8) = pk.v;
    }

    if (tid < 64) {
        float ssq = 0.f;
        #pragma unroll 16
        for (int d = 0; d < SUB_D; ++d) { float wv = tile[tid][d]; ssq += wv * wv; }
        csqr[g * K_CODES + k0 + tid] = ssq;
    }
}

__global__ __launch_bounds__(256) void perp_kernel(
    const float* __restrict__ wsum, int R, float* __restrict__ out)
{
    const int tid = threadIdx.x;
    const int lane = tid & 63, wave = tid >> 6;
    __shared__ float red[N_D][4];
    float part[N_D];
    #pragma unroll
    for (int g = 0; g < N_D; ++g) part[g] = 0.f;

    for (int g = 0; g < N_D; ++g) {
        for (int kk = tid; kk < K_CODES; kk += 256) {
            float s = 0.f;
            for (int r = 0; r < R; ++r) s += wsum[(size_t)r * (N_D * K_CODES) + g * K_CODES + kk];
            float p = s * (1.0f / N_TOK);
            part[g] += p * logf(p + 1e-10f);
        }
    }
    #pragma unroll
    for (int g = 0; g < N_D; ++g) {
        float v = part[g];
        #pragma unroll
        for (int off = 32; off; off >>= 1) v += __shfl_xor(v, off);
        if (lane == 0) red[g][wave] = v;
    }
    __syncthreads();
    if (tid == 0) {
        float perp = 0.f;
        #pragma unroll
        for (int g = 0; g < N_D; ++g) {
            float e = red[g][0] + red[g][1] + red[g][2] + red[g][3];
            perp += __expf(-e);
        }
        out[(size_t)B_SZ * D_FULL * T_SZ] = perp;
    }
}

extern "C" void kernel_launch(void* const* d_in, const int* in_sizes, int n_in,
                              void* d_out, int out_size, void* d_ws, size_t ws_size,
                              hipStream_t stream) {
    const float* x   = (const float*)d_in[0];
    const float* W1  = (const float*)d_in[1];
    const float* W2  = (const float*)d_in[2];
    const float* W3  = (const float*)d_in[3];
    const float* W4  = (const float*)d_in[4];
    const float* gum = (const float*)d_in[5];
    float* out = (float*)d_out;

    // ws layout: Wbf (512KB) | WTbf (512KB) | csqr (8KB) | wsum (R * 8KB)
    unsigned short* Wbf  = (unsigned short*)d_ws;
    unsigned short* WTbf = Wbf + (size_t)N_D * K_CODES * SUB_D;
    float* csqr = (float*)(WTbf + (size_t)N_D * K_CODES * SUB_D);
    float* wsum = csqr + N_D * K_CODES;

    size_t fixed = (size_t)N_D * K_CODES * SUB_D * 2 * 2 + (size_t)N_D * K_CODES * 4;
    size_t rem = (ws_size > fixed) ? (ws_size - fixed) : 0;
    int maxR = (int)(rem / ((size_t)N_D * K_CODES * 4));
    int R = 1;
    while (R * 2 <= maxR && R < 16) R *= 2;

    hipMemsetAsync(wsum, 0, (size_t)R * N_D * K_CODES * sizeof(float), stream);
    prep_kernel<<<dim3(4, 8), 256, 0, stream>>>(W1, W2, W3, W4, Wbf, WTbf, csqr);
    vq_kernel<<<dim3(N_TOK / TILE, N_D), 256, 0, stream>>>(x, Wbf, WTbf, csqr, gum, out, wsum, R - 1);
    perp_kernel<<<1, 256, 0, stream>>>(wsum, R, out);
}